// Round 14
// baseline (390.265 us; speedup 1.0000x reference)
//
#include <hip/hip_runtime.h>

#define N_NODES   50000
#define N_EDGES   800000
#define IN_DIM    128
#define HID_DIM   256
#define OUT_DIM   64
#define N_CLASSES 40

typedef __attribute__((ext_vector_type(8))) short short8;
typedef __attribute__((ext_vector_type(8))) unsigned short ushort8;
typedef __attribute__((ext_vector_type(4))) float f32x4;

__device__ inline short f2bf(float x) {
    unsigned u = __builtin_bit_cast(unsigned, x);
    unsigned r = (u + 0x7FFFu + ((u >> 16) & 1u)) >> 16;
    return (short)r;
}
__device__ inline float bf2f(unsigned short u) {
    unsigned v = ((unsigned)u) << 16;
    return __builtin_bit_cast(float, v);
}
// packed f32x2 -> bf16x2 (RTN-even), single VALU op
__device__ inline unsigned cvtpk(float lo, float hi) {
    unsigned r;
    asm("v_cvt_pk_bf16_f32 %0, %1, %2" : "=v"(r) : "v"(lo), "v"(hi));
    return r;
}
// swap bit-fields [5:4] <-> [3:2] of an 8-bit index (involution)
__device__ __host__ inline int swap23(int p) {
    return (p & 0xC3) | ((p >> 2) & 0x0C) | ((p << 2) & 0x30);
}

// ---------------- prep: zero counters, x->bf16, weights, ei->float ----------------

__global__ void k_prep(const float* __restrict__ x, const int* __restrict__ ei,
                       const float* __restrict__ W1, const float* __restrict__ W2,
                       const float* __restrict__ Wp1, const float* __restrict__ Wp2,
                       unsigned short* __restrict__ xb,
                       short* __restrict__ W1t, short* __restrict__ W2t,
                       short* __restrict__ Wp1t, short* __restrict__ Wp2t,
                       int* __restrict__ degi, int* __restrict__ cursor,
                       float* __restrict__ ei_out) {
    int i = blockIdx.x * 256 + threadIdx.x;
    if (i < N_NODES) { degi[i] = 0; cursor[i] = 0; }
    if (i < 128 * 256) {  // [128][256] -> [256][128]
        int k = i >> 8, n = i & 255;
        W1t[n * 128 + k]  = f2bf(W1[i]);
        Wp1t[n * 128 + k] = f2bf(Wp1[i]);
    }
    if (i < 256 * 64) {   // storage index p = i>>6, out col o = i&63 ; permuted k
        int p = i >> 6, o = i & 63;
        int h = swap23(p);
        W2t[o * 256 + p]  = f2bf(W2[h * 64 + o]);
        Wp2t[o * 256 + p] = f2bf(Wp2[h * 64 + o]);
    }
    if (i < N_NODES * IN_DIM / 4) {
        float4 v = ((const float4*)x)[i];
        uint2 u;
        u.x = cvtpk(v.x, v.y);
        u.y = cvtpk(v.z, v.w);
        *(uint2*)((unsigned short*)xb + (size_t)i * 4) = u;
    }
    if (i < (2 * N_EDGES) / 4) {
        int4 v = ((const int4*)ei)[i];
        float4 o = {(float)v.x, (float)v.y, (float)v.z, (float)v.w};
        ((float4*)ei_out)[i] = o;
    }
}

// ---------------- degree / CSR ----------------

__global__ void k_deg_count(const int* __restrict__ dst, int* __restrict__ degi) {
    int e = blockIdx.x * 256 + threadIdx.x;
    if (e < N_EDGES) atomicAdd(&degi[dst[e]], 1);
}

__global__ void k_scan_bsum(const int* __restrict__ vals, int n, int* __restrict__ bsum,
                            float* __restrict__ dinv) {
    __shared__ int sm[256];
    int t = threadIdx.x, i = blockIdx.x * 256 + t;
    int d = (i < n) ? vals[i] : 0;
    if (i < n) dinv[i] = rsqrtf((float)(d + 1));
    sm[t] = d;
    __syncthreads();
    for (int s = 128; s > 0; s >>= 1) {
        if (t < s) sm[t] += sm[t + s];
        __syncthreads();
    }
    if (t == 0) bsum[blockIdx.x] = sm[0];
}

__global__ void k_scan_bscan(int* __restrict__ bsum, int nb) {
    __shared__ int sm[256];
    int t = threadIdx.x;
    int orig = (t < nb) ? bsum[t] : 0;
    sm[t] = orig;
    __syncthreads();
    for (int off = 1; off < 256; off <<= 1) {
        int v = (t >= off) ? sm[t - off] : 0;
        __syncthreads();
        sm[t] += v;
        __syncthreads();
    }
    if (t < nb) bsum[t] = sm[t] - orig;
}

__global__ void k_scan_final(const int* __restrict__ vals, int n,
                             const int* __restrict__ bscan, int* __restrict__ out) {
    __shared__ int sm[256];
    int t = threadIdx.x, i = blockIdx.x * 256 + t;
    int orig = (i < n) ? vals[i] : 0;
    sm[t] = orig;
    __syncthreads();
    for (int off = 1; off < 256; off <<= 1) {
        int v = (t >= off) ? sm[t - off] : 0;
        __syncthreads();
        sm[t] += v;
        __syncthreads();
    }
    int excl = sm[t] - orig + bscan[blockIdx.x];
    if (i < n) out[i] = excl;
    if (i == n - 1) out[n] = excl + orig;
}

__global__ void k_csr_fill(const int* __restrict__ src, const int* __restrict__ dst,
                           const int* __restrict__ csr_off, int* __restrict__ cursor,
                           int* __restrict__ csr_src) {
    int e = blockIdx.x * 256 + threadIdx.x;
    if (e < N_EDGES) {
        int d = dst[e];
        int pos = csr_off[d] + atomicAdd(&cursor[d], 1);
        csr_src[pos] = src[e];
    }
}

// ---------------- agg0: xa = Anorm * xb  (128-dim bf16, wave/node, 4x unroll) ----

__global__ __launch_bounds__(256) void k_agg0(const unsigned short* __restrict__ xb,
                                              const float* __restrict__ dinv,
                                              const int* __restrict__ csr_off,
                                              const int* __restrict__ csr_src,
                                              unsigned short* __restrict__ xa) {
    const int v = blockIdx.x * 4 + (threadIdx.x >> 6);
    const int lane = threadIdx.x & 63;
    float dv = dinv[v];
    unsigned c = *(const unsigned*)(xb + (size_t)v * 128 + lane * 2);
    float a0 = bf2f((unsigned short)(c & 0xFFFF)) * dv;
    float a1 = bf2f((unsigned short)(c >> 16)) * dv;
    int beg = csr_off[v], end = csr_off[v + 1];
    for (int base = beg; base < end; base += 64) {
        int idx = base + lane;
        int sj = (idx < end) ? csr_src[idx] : 0;
        float dj = (idx < end) ? dinv[sj] : 0.f;
        int m = min(64, end - base);
        int j = 0;
        for (; j + 4 <= m; j += 4) {
            int s0 = __shfl(sj, j), s1 = __shfl(sj, j + 1);
            int s2 = __shfl(sj, j + 2), s3 = __shfl(sj, j + 3);
            float d0 = __shfl(dj, j), d1 = __shfl(dj, j + 1);
            float d2 = __shfl(dj, j + 2), d3 = __shfl(dj, j + 3);
            unsigned h0 = *(const unsigned*)(xb + (size_t)s0 * 128 + lane * 2);
            unsigned h1 = *(const unsigned*)(xb + (size_t)s1 * 128 + lane * 2);
            unsigned h2 = *(const unsigned*)(xb + (size_t)s2 * 128 + lane * 2);
            unsigned h3 = *(const unsigned*)(xb + (size_t)s3 * 128 + lane * 2);
            a0 += bf2f((unsigned short)(h0 & 0xFFFF)) * d0 + bf2f((unsigned short)(h1 & 0xFFFF)) * d1
                + bf2f((unsigned short)(h2 & 0xFFFF)) * d2 + bf2f((unsigned short)(h3 & 0xFFFF)) * d3;
            a1 += bf2f((unsigned short)(h0 >> 16)) * d0 + bf2f((unsigned short)(h1 >> 16)) * d1
                + bf2f((unsigned short)(h2 >> 16)) * d2 + bf2f((unsigned short)(h3 >> 16)) * d3;
        }
        for (; j < m; j++) {
            int s = __shfl(sj, j);
            float ds = __shfl(dj, j);
            unsigned hv = *(const unsigned*)(xb + (size_t)s * 128 + lane * 2);
            a0 += bf2f((unsigned short)(hv & 0xFFFF)) * ds;
            a1 += bf2f((unsigned short)(hv >> 16)) * ds;
        }
    }
    *(unsigned*)(xa + (size_t)v * 128 + lane * 2) = cvtpk(a0 * dv, a1 * dv);
}

// ---------------- agg2 + logits: f = Anorm*h2 + b2 ; logits = f@Wc + bc ----------

__global__ __launch_bounds__(256) void k_agg2(const unsigned short* __restrict__ h2b,
                                              const float* __restrict__ dinv,
                                              const int* __restrict__ csr_off,
                                              const int* __restrict__ csr_src,
                                              const float* __restrict__ b2,
                                              const float* __restrict__ Wc,
                                              const float* __restrict__ bc,
                                              float* __restrict__ f_out,
                                              unsigned short* __restrict__ fb,
                                              float* __restrict__ lg_out) {
    const int v = blockIdx.x * 4 + (threadIdx.x >> 6);
    const int lane = threadIdx.x & 63;
    float dv = dinv[v];
    float acc = bf2f(h2b[(size_t)v * 64 + lane]) * dv;
    int beg = csr_off[v], end = csr_off[v + 1];
    for (int base = beg; base < end; base += 64) {
        int idx = base + lane;
        int sj = (idx < end) ? csr_src[idx] : 0;
        float dj = (idx < end) ? dinv[sj] : 0.f;
        int m = min(64, end - base);
        int j = 0;
        for (; j + 4 <= m; j += 4) {
            int s0 = __shfl(sj, j), s1 = __shfl(sj, j + 1);
            int s2 = __shfl(sj, j + 2), s3 = __shfl(sj, j + 3);
            float d0 = __shfl(dj, j), d1 = __shfl(dj, j + 1);
            float d2 = __shfl(dj, j + 2), d3 = __shfl(dj, j + 3);
            float h0 = bf2f(h2b[(size_t)s0 * 64 + lane]);
            float h1 = bf2f(h2b[(size_t)s1 * 64 + lane]);
            float h2 = bf2f(h2b[(size_t)s2 * 64 + lane]);
            float h3 = bf2f(h2b[(size_t)s3 * 64 + lane]);
            acc += h0 * d0 + h1 * d1 + h2 * d2 + h3 * d3;
        }
        for (; j < m; j++) {
            int s = __shfl(sj, j);
            float ds = __shfl(dj, j);
            acc += bf2f(h2b[(size_t)s * 64 + lane]) * ds;
        }
    }
    float r = acc * dv + b2[lane];
    f_out[(size_t)v * 64 + lane] = r;
    fb[(size_t)v * 64 + lane] = (unsigned short)f2bf(r);
    bool act = lane < N_CLASSES;
    float lacc = act ? bc[lane] : 0.f;
    #pragma unroll
    for (int i2 = 0; i2 < 64; i2++) {
        float fi = __shfl(r, i2);
        if (act) lacc += fi * Wc[i2 * N_CLASSES + lane];
    }
    if (act) lg_out[(size_t)v * N_CLASSES + lane] = lacc;
}

// ---------------- fused GEMM1+GEMM2: h2b = relu(xa@W1+b1) @ W2, h1 in LDS only ----

__global__ __launch_bounds__(256) void k_gemm12(const unsigned short* __restrict__ xa,
                                                const short* __restrict__ W1t,
                                                const float* __restrict__ b1,
                                                const short* __restrict__ W2t,
                                                unsigned short* __restrict__ h2b) {
    __shared__ unsigned short xs[64 * 128];  // 16 KB
    __shared__ unsigned short hs[64 * 256];  // 32 KB (h1 tile, swizzled+permuted)
    const int t = threadIdx.x;
    const int lane = t & 63, wv = t >> 6, lr = lane & 15, lg = lane >> 4;
    const int nb = blockIdx.x * 64;

    #pragma unroll
    for (int i = 0; i < 4; i++) {
        int q = t + i * 256, row = q >> 4, seg = q & 15;
        int node = nb + row;
        ushort8 v = {0, 0, 0, 0, 0, 0, 0, 0};
        if (node < N_NODES) v = *(const ushort8*)(xa + (size_t)node * 128 + seg * 8);
        *(ushort8*)((char*)xs + ((row * 256 + seg * 16) ^ ((row & 7) << 4))) = v;
    }

    short8 A1[4][4];
    #pragma unroll
    for (int mi = 0; mi < 4; mi++)
        #pragma unroll
        for (int kt = 0; kt < 4; kt++)
            A1[mi][kt] = *(const short8*)(W1t + (size_t)(wv * 64 + mi * 16 + lr) * 128 + kt * 32 + lg * 8);
    float4 bb1[4];
    #pragma unroll
    for (int mi = 0; mi < 4; mi++)
        bb1[mi] = *(const float4*)(b1 + wv * 64 + mi * 16 + lg * 4);
    __syncthreads();

    // ---- L1: h1 tile -> hs (wave owns storage-col quarter wv*64) ----
    #pragma unroll
    for (int nj = 0; nj < 4; nj++) {
        short8 Bf[4];
        int nr = nj * 16 + lr;
        #pragma unroll
        for (int kt = 0; kt < 4; kt++)
            Bf[kt] = *(const short8*)((const char*)xs + ((nr * 256 + kt * 64 + lg * 16) ^ ((nr & 7) << 4)));
        #pragma unroll
        for (int mh = 0; mh < 2; mh++) {
            f32x4 a0 = {0.f, 0.f, 0.f, 0.f}, a1 = {0.f, 0.f, 0.f, 0.f};
            #pragma unroll
            for (int kt = 0; kt < 4; kt++) {
                a0 = __builtin_amdgcn_mfma_f32_16x16x32_bf16(A1[mh * 2 + 0][kt], Bf[kt], a0, 0, 0, 0);
                a1 = __builtin_amdgcn_mfma_f32_16x16x32_bf16(A1[mh * 2 + 1][kt], Bf[kt], a1, 0, 0, 0);
            }
            float4 b0 = bb1[mh * 2 + 0], b1v = bb1[mh * 2 + 1];
            uint4 pkv;
            pkv.x = cvtpk(fmaxf(a0[0] + b0.x, 0.f),  fmaxf(a0[1] + b0.y, 0.f));
            pkv.y = cvtpk(fmaxf(a0[2] + b0.z, 0.f),  fmaxf(a0[3] + b0.w, 0.f));
            pkv.z = cvtpk(fmaxf(a1[0] + b1v.x, 0.f), fmaxf(a1[1] + b1v.y, 0.f));
            pkv.w = cvtpk(fmaxf(a1[2] + b1v.z, 0.f), fmaxf(a1[3] + b1v.w, 0.f));
            *(uint4*)((char*)hs + ((nr * 512 + wv * 128 + lg * 32 + mh * 16) ^ ((nr & 7) << 4))) = pkv;
        }
    }

    short8 A2[8];  // W2t rows wv*16+lr (loads stay in flight across barrier)
    #pragma unroll
    for (int kt = 0; kt < 8; kt++)
        A2[kt] = *(const short8*)(W2t + (size_t)(wv * 16 + lr) * 256 + kt * 32 + lg * 8);
    asm volatile("s_waitcnt lgkmcnt(0)" ::: "memory");
    __builtin_amdgcn_s_barrier();

    // ---- L2: h2b (wave owns out-col quarter wv*16) ----
    #pragma unroll
    for (int nj = 0; nj < 4; nj++) {
        short8 Bh[8];
        int nr = nj * 16 + lr;
        #pragma unroll
        for (int kt = 0; kt < 8; kt++)
            Bh[kt] = *(const short8*)((const char*)hs + ((nr * 512 + kt * 64 + lg * 16) ^ ((nr & 7) << 4)));
        int node = nb + nr;
        f32x4 acc = {0.f, 0.f, 0.f, 0.f};
        #pragma unroll
        for (int kt = 0; kt < 8; kt++)
            acc = __builtin_amdgcn_mfma_f32_16x16x32_bf16(A2[kt], Bh[kt], acc, 0, 0, 0);
        if (node < N_NODES) {
            uint2 u;
            u.x = cvtpk(acc[0], acc[1]);
            u.y = cvtpk(acc[2], acc[3]);
            *(uint2*)(h2b + (size_t)node * 64 + wv * 16 + lg * 4) = u;
        }
    }
}

// ---------------- fused edge MLP: 2-deep pipelined register gather from fb --------
// Bf ping-pong (BfA/BfB): a row-gather is issued TWO iterations (~2000+ cy) before
// its L1 consumes it -> L3 gather latency (~700-900 cy) fully hidden. Index loads
// run three tiles ahead. hid double-buffered; one lgkm-only barrier per tile.

__global__ __launch_bounds__(256) void k_edge_mlpD(
        const unsigned short* __restrict__ fb,
        const int* __restrict__ src, const int* __restrict__ dst,
        const short* __restrict__ Wp1t, const float* __restrict__ bp1,
        const short* __restrict__ Wp2t, const float* __restrict__ bp2,
        float* __restrict__ out, int n_tiles) {
    __shared__ unsigned short hid_s[2][32 * 256];  // 2 x 16 KB

    const int t = threadIdx.x;
    const int lane = t & 63, wv = t >> 6, lr = lane & 15, lg = lane >> 4;

    short8 A1[4][4];
    #pragma unroll
    for (int mi = 0; mi < 4; mi++)
        #pragma unroll
        for (int kt = 0; kt < 4; kt++)
            A1[mi][kt] = *(const short8*)(Wp1t + (size_t)(wv * 64 + mi * 16 + lr) * 128 + kt * 32 + lg * 8);
    short8 A2[8];
    #pragma unroll
    for (int kt = 0; kt < 8; kt++)
        A2[kt] = *(const short8*)(Wp2t + (size_t)(wv * 16 + lr) * 256 + kt * 32 + lg * 8);
    float4 bb1[4];
    #pragma unroll
    for (int mi = 0; mi < 4; mi++)
        bb1[mi] = *(const float4*)(bp1 + wv * 64 + mi * 16 + lg * 4);
    const float4 bv2 = *(const float4*)(bp2 + wv * 16 + lg * 4);

    const int g = gridDim.x;
    const int t0 = blockIdx.x;
    if (t0 >= n_tiles) return;

    short8 BfA[2][4], BfB[2][4];
    int sA[2], dA[2];

    auto loadIdx = [&](int tl, int* s, int* d) {
        #pragma unroll
        for (int nj = 0; nj < 2; nj++) {
            int e = tl * 32 + nj * 16 + lr;
            s[nj] = src[e];
            d[nj] = dst[e];
        }
    };
    auto loadRows = [&](const int* s, const int* d, short8 Bf[2][4]) {
        #pragma unroll
        for (int nj = 0; nj < 2; nj++) {
            const unsigned short* srow = fb + (size_t)s[nj] * 64;
            const unsigned short* drow = fb + (size_t)d[nj] * 64;
            Bf[nj][0] = *(const short8*)(srow + lg * 8);
            Bf[nj][1] = *(const short8*)(srow + 32 + lg * 8);
            Bf[nj][2] = *(const short8*)(drow + lg * 8);
            Bf[nj][3] = *(const short8*)(drow + 32 + lg * 8);
        }
    };
    auto phaseL1 = [&](short8 Bf[2][4], unsigned short* hid) {
        #pragma unroll
        for (int nj = 0; nj < 2; nj++) {
            int er = nj * 16 + lr;
            #pragma unroll
            for (int mh = 0; mh < 2; mh++) {
                f32x4 a0 = {0.f, 0.f, 0.f, 0.f}, a1 = {0.f, 0.f, 0.f, 0.f};
                #pragma unroll
                for (int kt = 0; kt < 4; kt++) {
                    a0 = __builtin_amdgcn_mfma_f32_16x16x32_bf16(A1[mh * 2 + 0][kt], Bf[nj][kt], a0, 0, 0, 0);
                    a1 = __builtin_amdgcn_mfma_f32_16x16x32_bf16(A1[mh * 2 + 1][kt], Bf[nj][kt], a1, 0, 0, 0);
                }
                float4 b0 = bb1[mh * 2 + 0], b1v = bb1[mh * 2 + 1];
                uint4 pkv;
                pkv.x = cvtpk(fmaxf(a0[0] + b0.x, 0.f),  fmaxf(a0[1] + b0.y, 0.f));
                pkv.y = cvtpk(fmaxf(a0[2] + b0.z, 0.f),  fmaxf(a0[3] + b0.w, 0.f));
                pkv.z = cvtpk(fmaxf(a1[0] + b1v.x, 0.f), fmaxf(a1[1] + b1v.y, 0.f));
                pkv.w = cvtpk(fmaxf(a1[2] + b1v.z, 0.f), fmaxf(a1[3] + b1v.w, 0.f));
                *(uint4*)((char*)hid + ((er * 512 + wv * 128 + lg * 32 + mh * 16) ^ ((er & 7) << 4))) = pkv;
            }
        }
    };
    auto phaseL2 = [&](const unsigned short* hid, int tile) {
        #pragma unroll
        for (int nj = 0; nj < 2; nj++) {
            short8 Bh[8];
            int er = nj * 16 + lr;
            #pragma unroll
            for (int kt = 0; kt < 8; kt++)
                Bh[kt] = *(const short8*)((const char*)hid +
                             ((er * 512 + kt * 64 + lg * 16) ^ ((er & 7) << 4)));
            f32x4 acc = {0.f, 0.f, 0.f, 0.f};
            #pragma unroll
            for (int kt = 0; kt < 8; kt++)
                acc = __builtin_amdgcn_mfma_f32_16x16x32_bf16(A2[kt], Bh[kt], acc, 0, 0, 0);
            float4 o = {acc[0] + bv2.x, acc[1] + bv2.y, acc[2] + bv2.z, acc[3] + bv2.w};
            *(float4*)(out + (size_t)(tile * 32 + er) * 64 + wv * 16 + lg * 4) = o;
        }
    };

    // prologue: BfA = rows(t0), BfB = rows(t0+g), sA = idx(t0+2g)
    {
        int si[2], di[2];
        loadIdx(t0, si, di);
        loadRows(si, di, BfA);
        if (t0 + g < n_tiles) {
            loadIdx(t0 + g, si, di);
            loadRows(si, di, BfB);
        }
        if (t0 + 2 * g < n_tiles) loadIdx(t0 + 2 * g, sA, dA);
    }

    for (int tile = t0; tile < n_tiles; tile += 2 * g) {
        // ---- iter A: tile, BfA, hid[0] ----
        phaseL1(BfA, hid_s[0]);
        if (tile + 2 * g < n_tiles) loadRows(sA, dA, BfA);   // uses idx(tile+2g)
        if (tile + 3 * g < n_tiles) loadIdx(tile + 3 * g, sA, dA);
        asm volatile("s_waitcnt lgkmcnt(0)" ::: "memory");
        __builtin_amdgcn_s_barrier();
        phaseL2(hid_s[0], tile);

        // ---- iter B: tile+g, BfB, hid[1] ----
        int tb = tile + g;
        if (tb < n_tiles) {
            phaseL1(BfB, hid_s[1]);
            if (tb + 2 * g < n_tiles) loadRows(sA, dA, BfB); // uses idx(tb+2g)
            if (tb + 3 * g < n_tiles) loadIdx(tb + 3 * g, sA, dA);
            asm volatile("s_waitcnt lgkmcnt(0)" ::: "memory");
            __builtin_amdgcn_s_barrier();
            phaseL2(hid_s[1], tb);
        }
    }
}

// ---------------- launcher ----------------

extern "C" void kernel_launch(void* const* d_in, const int* in_sizes, int n_in,
                              void* d_out, int out_size, void* d_ws, size_t ws_size,
                              hipStream_t stream) {
    const float* x   = (const float*)d_in[0];
    const int*   ei  = (const int*)d_in[1];
    const float* W1  = (const float*)d_in[2];
    const float* b1  = (const float*)d_in[3];
    const float* W2  = (const float*)d_in[4];
    const float* b2  = (const float*)d_in[5];
    const float* Wp1 = (const float*)d_in[6];
    const float* bp1 = (const float*)d_in[7];
    const float* Wp2 = (const float*)d_in[8];
    const float* bp2 = (const float*)d_in[9];
    const float* Wc  = (const float*)d_in[10];
    const float* bc  = (const float*)d_in[11];

    const int* src = ei;
    const int* dst = ei + N_EDGES;

    float* out    = (float*)d_out;
    float* f_out  = out;                                   // [50000,64]
    float* ef_out = out + (size_t)N_NODES * OUT_DIM;       // [800000,64]
    float* lg_out = ef_out + (size_t)N_EDGES * OUT_DIM;    // [50000,40]
    float* ei_out = lg_out + (size_t)N_NODES * N_CLASSES;  // [2,800000]

    char* p = (char*)d_ws;
    auto alloc = [&](size_t bytes) -> char* {
        char* r = p;
        p += (bytes + 255) / 256 * 256;
        return r;
    };
    unsigned short* xb   = (unsigned short*)alloc((size_t)N_NODES * IN_DIM * 2);
    unsigned short* xa   = (unsigned short*)alloc((size_t)N_NODES * IN_DIM * 2);
    unsigned short* h2b  = (unsigned short*)alloc((size_t)N_NODES * OUT_DIM * 2);
    unsigned short* fb   = (unsigned short*)alloc((size_t)N_NODES * OUT_DIM * 2);
    int*   degi    = (int*)alloc((size_t)N_NODES * 4);
    float* dinv    = (float*)alloc((size_t)N_NODES * 4);
    int*   csr_off = (int*)alloc((size_t)(N_NODES + 1) * 4);
    int*   cursor  = (int*)alloc((size_t)N_NODES * 4);
    int*   csr_src = (int*)alloc((size_t)N_EDGES * 4);
    int*   bsum    = (int*)alloc(256 * 4);
    short* W1t     = (short*)alloc((size_t)256 * 128 * 2);
    short* W2t     = (short*)alloc((size_t)64 * 256 * 2);
    short* Wp1t    = (short*)alloc((size_t)256 * 128 * 2);
    short* Wp2t    = (short*)alloc((size_t)64 * 256 * 2);

    const int nbScan = (N_NODES + 255) / 256;  // 196

    k_prep<<<(N_NODES * IN_DIM / 4 + 255) / 256, 256, 0, stream>>>(
        x, ei, W1, W2, Wp1, Wp2, xb, W1t, W2t, Wp1t, Wp2t, degi, cursor, ei_out);
    k_deg_count<<<(N_EDGES + 255) / 256, 256, 0, stream>>>(dst, degi);
    k_scan_bsum<<<nbScan, 256, 0, stream>>>(degi, N_NODES, bsum, dinv);
    k_scan_bscan<<<1, 256, 0, stream>>>(bsum, nbScan);
    k_scan_final<<<nbScan, 256, 0, stream>>>(degi, N_NODES, bsum, csr_off);
    k_csr_fill<<<(N_EDGES + 255) / 256, 256, 0, stream>>>(src, dst, csr_off, cursor, csr_src);

    const int nbG = (N_NODES + 63) / 64;  // 782
    k_agg0<<<N_NODES / 4, 256, 0, stream>>>(xb, dinv, csr_off, csr_src, xa);
    k_gemm12<<<nbG, 256, 0, stream>>>(xa, W1t, b1, W2t, h2b);
    k_agg2<<<N_NODES / 4, 256, 0, stream>>>(h2b, dinv, csr_off, csr_src, b2, Wc, bc,
                                            f_out, fb, lg_out);

    k_edge_mlpD<<<768, 256, 0, stream>>>(fb, src, dst, Wp1t, bp1, Wp2t, bp2,
                                         ef_out, N_EDGES / 32);
}

// Round 15
// 385.394 us; speedup vs baseline: 1.0126x; 1.0126x over previous
//
#include <hip/hip_runtime.h>

#define N_NODES   50000
#define N_EDGES   800000
#define IN_DIM    128
#define HID_DIM   256
#define OUT_DIM   64
#define N_CLASSES 40

typedef __attribute__((ext_vector_type(8))) short short8;
typedef __attribute__((ext_vector_type(8))) unsigned short ushort8;
typedef __attribute__((ext_vector_type(4))) float f32x4;

__device__ inline short f2bf(float x) {
    unsigned u = __builtin_bit_cast(unsigned, x);
    unsigned r = (u + 0x7FFFu + ((u >> 16) & 1u)) >> 16;
    return (short)r;
}
__device__ inline float bf2f(unsigned short u) {
    unsigned v = ((unsigned)u) << 16;
    return __builtin_bit_cast(float, v);
}
// packed f32x2 -> bf16x2 (RTN-even), single VALU op
__device__ inline unsigned cvtpk(float lo, float hi) {
    unsigned r;
    asm("v_cvt_pk_bf16_f32 %0, %1, %2" : "=v"(r) : "v"(lo), "v"(hi));
    return r;
}
// swap bit-fields [5:4] <-> [3:2] of an 8-bit index (involution)
__device__ __host__ inline int swap23(int p) {
    return (p & 0xC3) | ((p >> 2) & 0x0C) | ((p << 2) & 0x30);
}

// ---------------- prep: zero counters, x->bf16, weights, ei->float ----------------

__global__ void k_prep(const float* __restrict__ x, const int* __restrict__ ei,
                       const float* __restrict__ W1, const float* __restrict__ W2,
                       const float* __restrict__ Wp1, const float* __restrict__ Wp2,
                       unsigned short* __restrict__ xb,
                       short* __restrict__ W1t, short* __restrict__ W2t,
                       short* __restrict__ Wp1t, short* __restrict__ Wp2t,
                       int* __restrict__ degi, int* __restrict__ cursor,
                       float* __restrict__ ei_out) {
    int i = blockIdx.x * 256 + threadIdx.x;
    if (i < N_NODES) { degi[i] = 0; cursor[i] = 0; }
    if (i < 128 * 256) {  // [128][256] -> [256][128]
        int k = i >> 8, n = i & 255;
        W1t[n * 128 + k]  = f2bf(W1[i]);
        Wp1t[n * 128 + k] = f2bf(Wp1[i]);
    }
    if (i < 256 * 64) {   // storage index p = i>>6, out col o = i&63 ; permuted k
        int p = i >> 6, o = i & 63;
        int h = swap23(p);
        W2t[o * 256 + p]  = f2bf(W2[h * 64 + o]);
        Wp2t[o * 256 + p] = f2bf(Wp2[h * 64 + o]);
    }
    if (i < N_NODES * IN_DIM / 4) {
        float4 v = ((const float4*)x)[i];
        uint2 u;
        u.x = cvtpk(v.x, v.y);
        u.y = cvtpk(v.z, v.w);
        *(uint2*)((unsigned short*)xb + (size_t)i * 4) = u;
    }
    if (i < (2 * N_EDGES) / 4) {
        int4 v = ((const int4*)ei)[i];
        float4 o = {(float)v.x, (float)v.y, (float)v.z, (float)v.w};
        ((float4*)ei_out)[i] = o;
    }
}

// ---------------- degree / CSR ----------------

__global__ void k_deg_count(const int* __restrict__ dst, int* __restrict__ degi) {
    int e = blockIdx.x * 256 + threadIdx.x;
    if (e < N_EDGES) atomicAdd(&degi[dst[e]], 1);
}

__global__ void k_scan_bsum(const int* __restrict__ vals, int n, int* __restrict__ bsum,
                            float* __restrict__ dinv) {
    __shared__ int sm[256];
    int t = threadIdx.x, i = blockIdx.x * 256 + t;
    int d = (i < n) ? vals[i] : 0;
    if (i < n) dinv[i] = rsqrtf((float)(d + 1));
    sm[t] = d;
    __syncthreads();
    for (int s = 128; s > 0; s >>= 1) {
        if (t < s) sm[t] += sm[t + s];
        __syncthreads();
    }
    if (t == 0) bsum[blockIdx.x] = sm[0];
}

__global__ void k_scan_bscan(int* __restrict__ bsum, int nb) {
    __shared__ int sm[256];
    int t = threadIdx.x;
    int orig = (t < nb) ? bsum[t] : 0;
    sm[t] = orig;
    __syncthreads();
    for (int off = 1; off < 256; off <<= 1) {
        int v = (t >= off) ? sm[t - off] : 0;
        __syncthreads();
        sm[t] += v;
        __syncthreads();
    }
    if (t < nb) bsum[t] = sm[t] - orig;
}

__global__ void k_scan_final(const int* __restrict__ vals, int n,
                             const int* __restrict__ bscan, int* __restrict__ out) {
    __shared__ int sm[256];
    int t = threadIdx.x, i = blockIdx.x * 256 + t;
    int orig = (i < n) ? vals[i] : 0;
    sm[t] = orig;
    __syncthreads();
    for (int off = 1; off < 256; off <<= 1) {
        int v = (t >= off) ? sm[t - off] : 0;
        __syncthreads();
        sm[t] += v;
        __syncthreads();
    }
    int excl = sm[t] - orig + bscan[blockIdx.x];
    if (i < n) out[i] = excl;
    if (i == n - 1) out[n] = excl + orig;
}

__global__ void k_csr_fill(const int* __restrict__ src, const int* __restrict__ dst,
                           const int* __restrict__ csr_off, int* __restrict__ cursor,
                           int* __restrict__ csr_src) {
    int e = blockIdx.x * 256 + threadIdx.x;
    if (e < N_EDGES) {
        int d = dst[e];
        int pos = csr_off[d] + atomicAdd(&cursor[d], 1);
        csr_src[pos] = src[e];
    }
}

// ---------------- agg0: xa = Anorm * xb  (128-dim bf16, wave/node, 8x unroll) ----

__global__ __launch_bounds__(256) void k_agg0(const unsigned short* __restrict__ xb,
                                              const float* __restrict__ dinv,
                                              const int* __restrict__ csr_off,
                                              const int* __restrict__ csr_src,
                                              unsigned short* __restrict__ xa) {
    const int v = blockIdx.x * 4 + (threadIdx.x >> 6);
    const int lane = threadIdx.x & 63;
    float dv = dinv[v];
    unsigned c = *(const unsigned*)(xb + (size_t)v * 128 + lane * 2);
    float a0 = bf2f((unsigned short)(c & 0xFFFF)) * dv;
    float a1 = bf2f((unsigned short)(c >> 16)) * dv;
    int beg = csr_off[v], end = csr_off[v + 1];
    for (int base = beg; base < end; base += 64) {
        int idx = base + lane;
        int sj = (idx < end) ? csr_src[idx] : 0;
        float dj = (idx < end) ? dinv[sj] : 0.f;
        int m = min(64, end - base);
        int j = 0;
        for (; j + 8 <= m; j += 8) {
            int s[8];
            float d[8];
            unsigned h[8];
            #pragma unroll
            for (int q = 0; q < 8; q++) {
                s[q] = __shfl(sj, j + q);
                d[q] = __shfl(dj, j + q);
            }
            #pragma unroll
            for (int q = 0; q < 8; q++)
                h[q] = *(const unsigned*)(xb + (size_t)s[q] * 128 + lane * 2);
            #pragma unroll
            for (int q = 0; q < 8; q++) {
                a0 += bf2f((unsigned short)(h[q] & 0xFFFF)) * d[q];
                a1 += bf2f((unsigned short)(h[q] >> 16)) * d[q];
            }
        }
        for (; j < m; j++) {
            int s = __shfl(sj, j);
            float ds = __shfl(dj, j);
            unsigned hv = *(const unsigned*)(xb + (size_t)s * 128 + lane * 2);
            a0 += bf2f((unsigned short)(hv & 0xFFFF)) * ds;
            a1 += bf2f((unsigned short)(hv >> 16)) * ds;
        }
    }
    *(unsigned*)(xa + (size_t)v * 128 + lane * 2) = cvtpk(a0 * dv, a1 * dv);
}

// ---------------- agg2 + logits: f = Anorm*h2 + b2 ; logits = f@Wc + bc ----------

__global__ __launch_bounds__(256) void k_agg2(const unsigned short* __restrict__ h2b,
                                              const float* __restrict__ dinv,
                                              const int* __restrict__ csr_off,
                                              const int* __restrict__ csr_src,
                                              const float* __restrict__ b2,
                                              const float* __restrict__ Wc,
                                              const float* __restrict__ bc,
                                              float* __restrict__ f_out,
                                              unsigned short* __restrict__ fb,
                                              float* __restrict__ lg_out) {
    const int v = blockIdx.x * 4 + (threadIdx.x >> 6);
    const int lane = threadIdx.x & 63;
    float dv = dinv[v];
    float acc = bf2f(h2b[(size_t)v * 64 + lane]) * dv;
    int beg = csr_off[v], end = csr_off[v + 1];
    for (int base = beg; base < end; base += 64) {
        int idx = base + lane;
        int sj = (idx < end) ? csr_src[idx] : 0;
        float dj = (idx < end) ? dinv[sj] : 0.f;
        int m = min(64, end - base);
        int j = 0;
        for (; j + 8 <= m; j += 8) {
            int s[8];
            float d[8];
            float h[8];
            #pragma unroll
            for (int q = 0; q < 8; q++) {
                s[q] = __shfl(sj, j + q);
                d[q] = __shfl(dj, j + q);
            }
            #pragma unroll
            for (int q = 0; q < 8; q++)
                h[q] = bf2f(h2b[(size_t)s[q] * 64 + lane]);
            #pragma unroll
            for (int q = 0; q < 8; q++) acc += h[q] * d[q];
        }
        for (; j < m; j++) {
            int s = __shfl(sj, j);
            float ds = __shfl(dj, j);
            acc += bf2f(h2b[(size_t)s * 64 + lane]) * ds;
        }
    }
    float r = acc * dv + b2[lane];
    f_out[(size_t)v * 64 + lane] = r;
    fb[(size_t)v * 64 + lane] = (unsigned short)f2bf(r);
    bool act = lane < N_CLASSES;
    float lacc = act ? bc[lane] : 0.f;
    #pragma unroll
    for (int i2 = 0; i2 < 64; i2++) {
        float fi = __shfl(r, i2);
        if (act) lacc += fi * Wc[i2 * N_CLASSES + lane];
    }
    if (act) lg_out[(size_t)v * N_CLASSES + lane] = lacc;
}

// ---------------- fused GEMM1+GEMM2: h2b = relu(xa@W1+b1) @ W2, h1 in LDS only ----

__global__ __launch_bounds__(256) void k_gemm12(const unsigned short* __restrict__ xa,
                                                const short* __restrict__ W1t,
                                                const float* __restrict__ b1,
                                                const short* __restrict__ W2t,
                                                unsigned short* __restrict__ h2b) {
    __shared__ unsigned short xs[64 * 128];  // 16 KB
    __shared__ unsigned short hs[64 * 256];  // 32 KB (h1 tile, swizzled+permuted)
    const int t = threadIdx.x;
    const int lane = t & 63, wv = t >> 6, lr = lane & 15, lg = lane >> 4;
    const int nb = blockIdx.x * 64;

    #pragma unroll
    for (int i = 0; i < 4; i++) {
        int q = t + i * 256, row = q >> 4, seg = q & 15;
        int node = nb + row;
        ushort8 v = {0, 0, 0, 0, 0, 0, 0, 0};
        if (node < N_NODES) v = *(const ushort8*)(xa + (size_t)node * 128 + seg * 8);
        *(ushort8*)((char*)xs + ((row * 256 + seg * 16) ^ ((row & 7) << 4))) = v;
    }

    short8 A1[4][4];
    #pragma unroll
    for (int mi = 0; mi < 4; mi++)
        #pragma unroll
        for (int kt = 0; kt < 4; kt++)
            A1[mi][kt] = *(const short8*)(W1t + (size_t)(wv * 64 + mi * 16 + lr) * 128 + kt * 32 + lg * 8);
    float4 bb1[4];
    #pragma unroll
    for (int mi = 0; mi < 4; mi++)
        bb1[mi] = *(const float4*)(b1 + wv * 64 + mi * 16 + lg * 4);
    __syncthreads();

    // ---- L1: h1 tile -> hs (wave owns storage-col quarter wv*64) ----
    #pragma unroll
    for (int nj = 0; nj < 4; nj++) {
        short8 Bf[4];
        int nr = nj * 16 + lr;
        #pragma unroll
        for (int kt = 0; kt < 4; kt++)
            Bf[kt] = *(const short8*)((const char*)xs + ((nr * 256 + kt * 64 + lg * 16) ^ ((nr & 7) << 4)));
        #pragma unroll
        for (int mh = 0; mh < 2; mh++) {
            f32x4 a0 = {0.f, 0.f, 0.f, 0.f}, a1 = {0.f, 0.f, 0.f, 0.f};
            #pragma unroll
            for (int kt = 0; kt < 4; kt++) {
                a0 = __builtin_amdgcn_mfma_f32_16x16x32_bf16(A1[mh * 2 + 0][kt], Bf[kt], a0, 0, 0, 0);
                a1 = __builtin_amdgcn_mfma_f32_16x16x32_bf16(A1[mh * 2 + 1][kt], Bf[kt], a1, 0, 0, 0);
            }
            float4 b0 = bb1[mh * 2 + 0], b1v = bb1[mh * 2 + 1];
            uint4 pkv;
            pkv.x = cvtpk(fmaxf(a0[0] + b0.x, 0.f),  fmaxf(a0[1] + b0.y, 0.f));
            pkv.y = cvtpk(fmaxf(a0[2] + b0.z, 0.f),  fmaxf(a0[3] + b0.w, 0.f));
            pkv.z = cvtpk(fmaxf(a1[0] + b1v.x, 0.f), fmaxf(a1[1] + b1v.y, 0.f));
            pkv.w = cvtpk(fmaxf(a1[2] + b1v.z, 0.f), fmaxf(a1[3] + b1v.w, 0.f));
            *(uint4*)((char*)hs + ((nr * 512 + wv * 128 + lg * 32 + mh * 16) ^ ((nr & 7) << 4))) = pkv;
        }
    }

    short8 A2[8];  // W2t rows wv*16+lr (loads stay in flight across barrier)
    #pragma unroll
    for (int kt = 0; kt < 8; kt++)
        A2[kt] = *(const short8*)(W2t + (size_t)(wv * 16 + lr) * 256 + kt * 32 + lg * 8);
    asm volatile("s_waitcnt lgkmcnt(0)" ::: "memory");
    __builtin_amdgcn_s_barrier();

    // ---- L2: h2b (wave owns out-col quarter wv*16) ----
    #pragma unroll
    for (int nj = 0; nj < 4; nj++) {
        short8 Bh[8];
        int nr = nj * 16 + lr;
        #pragma unroll
        for (int kt = 0; kt < 8; kt++)
            Bh[kt] = *(const short8*)((const char*)hs + ((nr * 512 + kt * 64 + lg * 16) ^ ((nr & 7) << 4)));
        int node = nb + nr;
        f32x4 acc = {0.f, 0.f, 0.f, 0.f};
        #pragma unroll
        for (int kt = 0; kt < 8; kt++)
            acc = __builtin_amdgcn_mfma_f32_16x16x32_bf16(A2[kt], Bh[kt], acc, 0, 0, 0);
        if (node < N_NODES) {
            uint2 u;
            u.x = cvtpk(acc[0], acc[1]);
            u.y = cvtpk(acc[2], acc[3]);
            *(uint2*)(h2b + (size_t)node * 64 + wv * 16 + lg * 4) = u;
        }
    }
}

// ---------------- fused edge MLP: pipelined, direct register gather from fb -------
// R13 structure (best measured). Grid 2048 = exactly 2 full residency rounds at
// 4 blocks/CU (R14 lesson: grid granularity, not pipeline depth, was the lever).

__global__ __launch_bounds__(256) void k_edge_mlpC(
        const unsigned short* __restrict__ fb,
        const int* __restrict__ src, const int* __restrict__ dst,
        const short* __restrict__ Wp1t, const float* __restrict__ bp1,
        const short* __restrict__ Wp2t, const float* __restrict__ bp2,
        float* __restrict__ out, int n_tiles) {
    __shared__ unsigned short hid_s[2][32 * 256];  // 2 x 16 KB

    const int t = threadIdx.x;
    const int lane = t & 63, wv = t >> 6, lr = lane & 15, lg = lane >> 4;

    short8 A1[4][4];
    #pragma unroll
    for (int mi = 0; mi < 4; mi++)
        #pragma unroll
        for (int kt = 0; kt < 4; kt++)
            A1[mi][kt] = *(const short8*)(Wp1t + (size_t)(wv * 64 + mi * 16 + lr) * 128 + kt * 32 + lg * 8);
    short8 A2[8];
    #pragma unroll
    for (int kt = 0; kt < 8; kt++)
        A2[kt] = *(const short8*)(Wp2t + (size_t)(wv * 16 + lr) * 256 + kt * 32 + lg * 8);
    float4 bb1[4];
    #pragma unroll
    for (int mi = 0; mi < 4; mi++)
        bb1[mi] = *(const float4*)(bp1 + wv * 64 + mi * 16 + lg * 4);
    const float4 bv2 = *(const float4*)(bp2 + wv * 16 + lg * 4);

    int tile = blockIdx.x;
    if (tile >= n_tiles) return;
    const int g = gridDim.x;

    short8 Bf[2][4];
    {
        int sC[2], dC[2];
        #pragma unroll
        for (int nj = 0; nj < 2; nj++) {
            int e = tile * 32 + nj * 16 + lr;
            sC[nj] = src[e];
            dC[nj] = dst[e];
        }
        #pragma unroll
        for (int nj = 0; nj < 2; nj++) {
            const unsigned short* srow = fb + (size_t)sC[nj] * 64;
            const unsigned short* drow = fb + (size_t)dC[nj] * 64;
            Bf[nj][0] = *(const short8*)(srow + lg * 8);
            Bf[nj][1] = *(const short8*)(srow + 32 + lg * 8);
            Bf[nj][2] = *(const short8*)(drow + lg * 8);
            Bf[nj][3] = *(const short8*)(drow + 32 + lg * 8);
        }
    }
    int sA[2], dA[2];
    {
        int tn = tile + g;
        if (tn < n_tiles) {
            #pragma unroll
            for (int nj = 0; nj < 2; nj++) {
                int e = tn * 32 + nj * 16 + lr;
                sA[nj] = src[e];
                dA[nj] = dst[e];
            }
        }
    }

    int cur = 0;
    for (; tile < n_tiles; tile += g) {
        // ---- L1 phase: consume Bf, write hid_s[cur] ----
        #pragma unroll
        for (int nj = 0; nj < 2; nj++) {
            int er = nj * 16 + lr;
            #pragma unroll
            for (int mh = 0; mh < 2; mh++) {
                f32x4 a0 = {0.f, 0.f, 0.f, 0.f}, a1 = {0.f, 0.f, 0.f, 0.f};
                #pragma unroll
                for (int kt = 0; kt < 4; kt++) {
                    a0 = __builtin_amdgcn_mfma_f32_16x16x32_bf16(A1[mh * 2 + 0][kt], Bf[nj][kt], a0, 0, 0, 0);
                    a1 = __builtin_amdgcn_mfma_f32_16x16x32_bf16(A1[mh * 2 + 1][kt], Bf[nj][kt], a1, 0, 0, 0);
                }
                float4 b0 = bb1[mh * 2 + 0], b1v = bb1[mh * 2 + 1];
                uint4 pkv;
                pkv.x = cvtpk(fmaxf(a0[0] + b0.x, 0.f),  fmaxf(a0[1] + b0.y, 0.f));
                pkv.y = cvtpk(fmaxf(a0[2] + b0.z, 0.f),  fmaxf(a0[3] + b0.w, 0.f));
                pkv.z = cvtpk(fmaxf(a1[0] + b1v.x, 0.f), fmaxf(a1[1] + b1v.y, 0.f));
                pkv.w = cvtpk(fmaxf(a1[2] + b1v.z, 0.f), fmaxf(a1[3] + b1v.w, 0.f));
                *(uint4*)((char*)hid_s[cur] +
                    ((er * 512 + wv * 128 + lg * 32 + mh * 16) ^ ((er & 7) << 4))) = pkv;
            }
        }

        // ---- prefetch Bf(tile+g) (addresses ready from sA/dA) ----
        int tn = tile + g;
        if (tn < n_tiles) {
            #pragma unroll
            for (int nj = 0; nj < 2; nj++) {
                const unsigned short* srow = fb + (size_t)sA[nj] * 64;
                const unsigned short* drow = fb + (size_t)dA[nj] * 64;
                Bf[nj][0] = *(const short8*)(srow + lg * 8);
                Bf[nj][1] = *(const short8*)(srow + 32 + lg * 8);
                Bf[nj][2] = *(const short8*)(drow + lg * 8);
                Bf[nj][3] = *(const short8*)(drow + 32 + lg * 8);
            }
        }
        // ---- prefetch idx(tile+2g) ----
        int tnn = tile + 2 * g;
        if (tnn < n_tiles) {
            #pragma unroll
            for (int nj = 0; nj < 2; nj++) {
                int e = tnn * 32 + nj * 16 + lr;
                sA[nj] = src[e];
                dA[nj] = dst[e];
            }
        }

        asm volatile("s_waitcnt lgkmcnt(0)" ::: "memory");
        __builtin_amdgcn_s_barrier();

        // ---- L2 phase ----
        #pragma unroll
        for (int nj = 0; nj < 2; nj++) {
            short8 Bh[8];
            int er = nj * 16 + lr;
            #pragma unroll
            for (int kt = 0; kt < 8; kt++)
                Bh[kt] = *(const short8*)((const char*)hid_s[cur] +
                             ((er * 512 + kt * 64 + lg * 16) ^ ((er & 7) << 4)));
            f32x4 acc = {0.f, 0.f, 0.f, 0.f};
            #pragma unroll
            for (int kt = 0; kt < 8; kt++)
                acc = __builtin_amdgcn_mfma_f32_16x16x32_bf16(A2[kt], Bh[kt], acc, 0, 0, 0);
            float4 o = {acc[0] + bv2.x, acc[1] + bv2.y, acc[2] + bv2.z, acc[3] + bv2.w};
            *(float4*)(out + (size_t)(tile * 32 + er) * 64 + wv * 16 + lg * 4) = o;
        }
        cur ^= 1;
    }
}

// ---------------- launcher ----------------

extern "C" void kernel_launch(void* const* d_in, const int* in_sizes, int n_in,
                              void* d_out, int out_size, void* d_ws, size_t ws_size,
                              hipStream_t stream) {
    const float* x   = (const float*)d_in[0];
    const int*   ei  = (const int*)d_in[1];
    const float* W1  = (const float*)d_in[2];
    const float* b1  = (const float*)d_in[3];
    const float* W2  = (const float*)d_in[4];
    const float* b2  = (const float*)d_in[5];
    const float* Wp1 = (const float*)d_in[6];
    const float* bp1 = (const float*)d_in[7];
    const float* Wp2 = (const float*)d_in[8];
    const float* bp2 = (const float*)d_in[9];
    const float* Wc  = (const float*)d_in[10];
    const float* bc  = (const float*)d_in[11];

    const int* src = ei;
    const int* dst = ei + N_EDGES;

    float* out    = (float*)d_out;
    float* f_out  = out;                                   // [50000,64]
    float* ef_out = out + (size_t)N_NODES * OUT_DIM;       // [800000,64]
    float* lg_out = ef_out + (size_t)N_EDGES * OUT_DIM;    // [50000,40]
    float* ei_out = lg_out + (size_t)N_NODES * N_CLASSES;  // [2,800000]

    char* p = (char*)d_ws;
    auto alloc = [&](size_t bytes) -> char* {
        char* r = p;
        p += (bytes + 255) / 256 * 256;
        return r;
    };
    unsigned short* xb   = (unsigned short*)alloc((size_t)N_NODES * IN_DIM * 2);
    unsigned short* xa   = (unsigned short*)alloc((size_t)N_NODES * IN_DIM * 2);
    unsigned short* h2b  = (unsigned short*)alloc((size_t)N_NODES * OUT_DIM * 2);
    unsigned short* fb   = (unsigned short*)alloc((size_t)N_NODES * OUT_DIM * 2);
    int*   degi    = (int*)alloc((size_t)N_NODES * 4);
    float* dinv    = (float*)alloc((size_t)N_NODES * 4);
    int*   csr_off = (int*)alloc((size_t)(N_NODES + 1) * 4);
    int*   cursor  = (int*)alloc((size_t)N_NODES * 4);
    int*   csr_src = (int*)alloc((size_t)N_EDGES * 4);
    int*   bsum    = (int*)alloc(256 * 4);
    short* W1t     = (short*)alloc((size_t)256 * 128 * 2);
    short* W2t     = (short*)alloc((size_t)64 * 256 * 2);
    short* Wp1t    = (short*)alloc((size_t)256 * 128 * 2);
    short* Wp2t    = (short*)alloc((size_t)64 * 256 * 2);

    const int nbScan = (N_NODES + 255) / 256;  // 196

    k_prep<<<(N_NODES * IN_DIM / 4 + 255) / 256, 256, 0, stream>>>(
        x, ei, W1, W2, Wp1, Wp2, xb, W1t, W2t, Wp1t, Wp2t, degi, cursor, ei_out);
    k_deg_count<<<(N_EDGES + 255) / 256, 256, 0, stream>>>(dst, degi);
    k_scan_bsum<<<nbScan, 256, 0, stream>>>(degi, N_NODES, bsum, dinv);
    k_scan_bscan<<<1, 256, 0, stream>>>(bsum, nbScan);
    k_scan_final<<<nbScan, 256, 0, stream>>>(degi, N_NODES, bsum, csr_off);
    k_csr_fill<<<(N_EDGES + 255) / 256, 256, 0, stream>>>(src, dst, csr_off, cursor, csr_src);

    const int nbG = (N_NODES + 63) / 64;  // 782
    k_agg0<<<N_NODES / 4, 256, 0, stream>>>(xb, dinv, csr_off, csr_src, xa);
    k_gemm12<<<nbG, 256, 0, stream>>>(xa, W1t, b1, W2t, h2b);
    k_agg2<<<N_NODES / 4, 256, 0, stream>>>(h2b, dinv, csr_off, csr_src, b2, Wc, bc,
                                            f_out, fb, lg_out);

    k_edge_mlpC<<<2048, 256, 0, stream>>>(fb, src, dst, Wp1t, bp1, Wp2t, bp2,
                                          ef_out, N_EDGES / 32);
}

// Round 16
// 370.953 us; speedup vs baseline: 1.0521x; 1.0389x over previous
//
#include <hip/hip_runtime.h>

#define N_NODES   50000
#define N_EDGES   800000
#define IN_DIM    128
#define HID_DIM   256
#define OUT_DIM   64
#define N_CLASSES 40

typedef __attribute__((ext_vector_type(8))) short short8;
typedef __attribute__((ext_vector_type(8))) unsigned short ushort8;
typedef __attribute__((ext_vector_type(4))) float f32x4;

__device__ inline short f2bf(float x) {
    unsigned u = __builtin_bit_cast(unsigned, x);
    unsigned r = (u + 0x7FFFu + ((u >> 16) & 1u)) >> 16;
    return (short)r;
}
__device__ inline float bf2f(unsigned short u) {
    unsigned v = ((unsigned)u) << 16;
    return __builtin_bit_cast(float, v);
}
// packed f32x2 -> bf16x2 (RTN-even), single VALU op
__device__ inline unsigned cvtpk(float lo, float hi) {
    unsigned r;
    asm("v_cvt_pk_bf16_f32 %0, %1, %2" : "=v"(r) : "v"(lo), "v"(hi));
    return r;
}
// swap bit-fields [5:4] <-> [3:2] of an 8-bit index (involution)
__device__ __host__ inline int swap23(int p) {
    return (p & 0xC3) | ((p >> 2) & 0x0C) | ((p << 2) & 0x30);
}

// ---------------- prep: zero counters, x->bf16, weights, ei->float ----------------

__global__ void k_prep(const float* __restrict__ x, const int* __restrict__ ei,
                       const float* __restrict__ W1, const float* __restrict__ W2,
                       const float* __restrict__ Wp1, const float* __restrict__ Wp2,
                       unsigned short* __restrict__ xb,
                       short* __restrict__ W1t, short* __restrict__ W2t,
                       short* __restrict__ Wp1t, short* __restrict__ Wp2t,
                       int* __restrict__ degi, int* __restrict__ cursor,
                       float* __restrict__ ei_out) {
    int i = blockIdx.x * 256 + threadIdx.x;
    if (i < N_NODES) { degi[i] = 0; cursor[i] = 0; }
    if (i < 128 * 256) {  // [128][256] -> [256][128]
        int k = i >> 8, n = i & 255;
        W1t[n * 128 + k]  = f2bf(W1[i]);
        Wp1t[n * 128 + k] = f2bf(Wp1[i]);
    }
    if (i < 256 * 64) {   // storage index p = i>>6, out col o = i&63 ; permuted k
        int p = i >> 6, o = i & 63;
        int h = swap23(p);
        W2t[o * 256 + p]  = f2bf(W2[h * 64 + o]);
        Wp2t[o * 256 + p] = f2bf(Wp2[h * 64 + o]);
    }
    if (i < N_NODES * IN_DIM / 4) {
        float4 v = ((const float4*)x)[i];
        uint2 u;
        u.x = cvtpk(v.x, v.y);
        u.y = cvtpk(v.z, v.w);
        *(uint2*)((unsigned short*)xb + (size_t)i * 4) = u;
    }
    if (i < (2 * N_EDGES) / 4) {
        int4 v = ((const int4*)ei)[i];
        float4 o = {(float)v.x, (float)v.y, (float)v.z, (float)v.w};
        ((float4*)ei_out)[i] = o;
    }
}

// ---------------- degree / CSR ----------------

__global__ void k_deg_count(const int* __restrict__ dst, int* __restrict__ degi) {
    int e = blockIdx.x * 256 + threadIdx.x;
    if (e < N_EDGES) atomicAdd(&degi[dst[e]], 1);
}

__global__ void k_scan_bsum(const int* __restrict__ vals, int n, int* __restrict__ bsum,
                            float* __restrict__ dinv) {
    __shared__ int sm[256];
    int t = threadIdx.x, i = blockIdx.x * 256 + t;
    int d = (i < n) ? vals[i] : 0;
    if (i < n) dinv[i] = rsqrtf((float)(d + 1));
    sm[t] = d;
    __syncthreads();
    for (int s = 128; s > 0; s >>= 1) {
        if (t < s) sm[t] += sm[t + s];
        __syncthreads();
    }
    if (t == 0) bsum[blockIdx.x] = sm[0];
}

__global__ void k_scan_bscan(int* __restrict__ bsum, int nb) {
    __shared__ int sm[256];
    int t = threadIdx.x;
    int orig = (t < nb) ? bsum[t] : 0;
    sm[t] = orig;
    __syncthreads();
    for (int off = 1; off < 256; off <<= 1) {
        int v = (t >= off) ? sm[t - off] : 0;
        __syncthreads();
        sm[t] += v;
        __syncthreads();
    }
    if (t < nb) bsum[t] = sm[t] - orig;
}

__global__ void k_scan_final(const int* __restrict__ vals, int n,
                             const int* __restrict__ bscan, int* __restrict__ out) {
    __shared__ int sm[256];
    int t = threadIdx.x, i = blockIdx.x * 256 + t;
    int orig = (i < n) ? vals[i] : 0;
    sm[t] = orig;
    __syncthreads();
    for (int off = 1; off < 256; off <<= 1) {
        int v = (t >= off) ? sm[t - off] : 0;
        __syncthreads();
        sm[t] += v;
        __syncthreads();
    }
    int excl = sm[t] - orig + bscan[blockIdx.x];
    if (i < n) out[i] = excl;
    if (i == n - 1) out[n] = excl + orig;
}

__global__ void k_csr_fill(const int* __restrict__ src, const int* __restrict__ dst,
                           const int* __restrict__ csr_off, int* __restrict__ cursor,
                           int* __restrict__ csr_src) {
    int e = blockIdx.x * 256 + threadIdx.x;
    if (e < N_EDGES) {
        int d = dst[e];
        int pos = csr_off[d] + atomicAdd(&cursor[d], 1);
        csr_src[pos] = src[e];
    }
}

// ---------------- agg0: xa = Anorm * xb  (128-dim bf16, wave/node, 4x unroll) ----

__global__ __launch_bounds__(256) void k_agg0(const unsigned short* __restrict__ xb,
                                              const float* __restrict__ dinv,
                                              const int* __restrict__ csr_off,
                                              const int* __restrict__ csr_src,
                                              unsigned short* __restrict__ xa) {
    const int v = blockIdx.x * 4 + (threadIdx.x >> 6);
    const int lane = threadIdx.x & 63;
    float dv = dinv[v];
    unsigned c = *(const unsigned*)(xb + (size_t)v * 128 + lane * 2);
    float a0 = bf2f((unsigned short)(c & 0xFFFF)) * dv;
    float a1 = bf2f((unsigned short)(c >> 16)) * dv;
    int beg = csr_off[v], end = csr_off[v + 1];
    for (int base = beg; base < end; base += 64) {
        int idx = base + lane;
        int sj = (idx < end) ? csr_src[idx] : 0;
        float dj = (idx < end) ? dinv[sj] : 0.f;
        int m = min(64, end - base);
        int j = 0;
        for (; j + 4 <= m; j += 4) {
            int s0 = __shfl(sj, j), s1 = __shfl(sj, j + 1);
            int s2 = __shfl(sj, j + 2), s3 = __shfl(sj, j + 3);
            float d0 = __shfl(dj, j), d1 = __shfl(dj, j + 1);
            float d2 = __shfl(dj, j + 2), d3 = __shfl(dj, j + 3);
            unsigned h0 = *(const unsigned*)(xb + (size_t)s0 * 128 + lane * 2);
            unsigned h1 = *(const unsigned*)(xb + (size_t)s1 * 128 + lane * 2);
            unsigned h2 = *(const unsigned*)(xb + (size_t)s2 * 128 + lane * 2);
            unsigned h3 = *(const unsigned*)(xb + (size_t)s3 * 128 + lane * 2);
            a0 += bf2f((unsigned short)(h0 & 0xFFFF)) * d0 + bf2f((unsigned short)(h1 & 0xFFFF)) * d1
                + bf2f((unsigned short)(h2 & 0xFFFF)) * d2 + bf2f((unsigned short)(h3 & 0xFFFF)) * d3;
            a1 += bf2f((unsigned short)(h0 >> 16)) * d0 + bf2f((unsigned short)(h1 >> 16)) * d1
                + bf2f((unsigned short)(h2 >> 16)) * d2 + bf2f((unsigned short)(h3 >> 16)) * d3;
        }
        for (; j < m; j++) {
            int s = __shfl(sj, j);
            float ds = __shfl(dj, j);
            unsigned hv = *(const unsigned*)(xb + (size_t)s * 128 + lane * 2);
            a0 += bf2f((unsigned short)(hv & 0xFFFF)) * ds;
            a1 += bf2f((unsigned short)(hv >> 16)) * ds;
        }
    }
    *(unsigned*)(xa + (size_t)v * 128 + lane * 2) = cvtpk(a0 * dv, a1 * dv);
}

// ---------------- agg2 + logits: f = Anorm*h2 + b2 ; logits = f@Wc + bc ----------

__global__ __launch_bounds__(256) void k_agg2(const unsigned short* __restrict__ h2b,
                                              const float* __restrict__ dinv,
                                              const int* __restrict__ csr_off,
                                              const int* __restrict__ csr_src,
                                              const float* __restrict__ b2,
                                              const float* __restrict__ Wc,
                                              const float* __restrict__ bc,
                                              float* __restrict__ f_out,
                                              unsigned short* __restrict__ fb,
                                              float* __restrict__ lg_out) {
    const int v = blockIdx.x * 4 + (threadIdx.x >> 6);
    const int lane = threadIdx.x & 63;
    float dv = dinv[v];
    float acc = bf2f(h2b[(size_t)v * 64 + lane]) * dv;
    int beg = csr_off[v], end = csr_off[v + 1];
    for (int base = beg; base < end; base += 64) {
        int idx = base + lane;
        int sj = (idx < end) ? csr_src[idx] : 0;
        float dj = (idx < end) ? dinv[sj] : 0.f;
        int m = min(64, end - base);
        int j = 0;
        for (; j + 4 <= m; j += 4) {
            int s0 = __shfl(sj, j), s1 = __shfl(sj, j + 1);
            int s2 = __shfl(sj, j + 2), s3 = __shfl(sj, j + 3);
            float d0 = __shfl(dj, j), d1 = __shfl(dj, j + 1);
            float d2 = __shfl(dj, j + 2), d3 = __shfl(dj, j + 3);
            float h0 = bf2f(h2b[(size_t)s0 * 64 + lane]);
            float h1 = bf2f(h2b[(size_t)s1 * 64 + lane]);
            float h2 = bf2f(h2b[(size_t)s2 * 64 + lane]);
            float h3 = bf2f(h2b[(size_t)s3 * 64 + lane]);
            acc += h0 * d0 + h1 * d1 + h2 * d2 + h3 * d3;
        }
        for (; j < m; j++) {
            int s = __shfl(sj, j);
            float ds = __shfl(dj, j);
            acc += bf2f(h2b[(size_t)s * 64 + lane]) * ds;
        }
    }
    float r = acc * dv + b2[lane];
    f_out[(size_t)v * 64 + lane] = r;
    fb[(size_t)v * 64 + lane] = (unsigned short)f2bf(r);
    bool act = lane < N_CLASSES;
    float lacc = act ? bc[lane] : 0.f;
    #pragma unroll
    for (int i2 = 0; i2 < 64; i2++) {
        float fi = __shfl(r, i2);
        if (act) lacc += fi * Wc[i2 * N_CLASSES + lane];
    }
    if (act) lg_out[(size_t)v * N_CLASSES + lane] = lacc;
}

// ---------------- fused GEMM1+GEMM2: h2b = relu(xa@W1+b1) @ W2, h1 in LDS only ----
// hs rows are 512 B: swizzle widened to (nr&15)<<4 (16-slot spread, ~2-way).

__global__ __launch_bounds__(256) void k_gemm12(const unsigned short* __restrict__ xa,
                                                const short* __restrict__ W1t,
                                                const float* __restrict__ b1,
                                                const short* __restrict__ W2t,
                                                unsigned short* __restrict__ h2b) {
    __shared__ unsigned short xs[64 * 128];  // 16 KB
    __shared__ unsigned short hs[64 * 256];  // 32 KB (h1 tile, swizzled+permuted)
    const int t = threadIdx.x;
    const int lane = t & 63, wv = t >> 6, lr = lane & 15, lg = lane >> 4;
    const int nb = blockIdx.x * 64;

    #pragma unroll
    for (int i = 0; i < 4; i++) {
        int q = t + i * 256, row = q >> 4, seg = q & 15;
        int node = nb + row;
        ushort8 v = {0, 0, 0, 0, 0, 0, 0, 0};
        if (node < N_NODES) v = *(const ushort8*)(xa + (size_t)node * 128 + seg * 8);
        *(ushort8*)((char*)xs + ((row * 256 + seg * 16) ^ ((row & 7) << 4))) = v;
    }

    short8 A1[4][4];
    #pragma unroll
    for (int mi = 0; mi < 4; mi++)
        #pragma unroll
        for (int kt = 0; kt < 4; kt++)
            A1[mi][kt] = *(const short8*)(W1t + (size_t)(wv * 64 + mi * 16 + lr) * 128 + kt * 32 + lg * 8);
    float4 bb1[4];
    #pragma unroll
    for (int mi = 0; mi < 4; mi++)
        bb1[mi] = *(const float4*)(b1 + wv * 64 + mi * 16 + lg * 4);
    __syncthreads();

    // ---- L1: h1 tile -> hs (wave owns storage-col quarter wv*64) ----
    #pragma unroll
    for (int nj = 0; nj < 4; nj++) {
        short8 Bf[4];
        int nr = nj * 16 + lr;
        #pragma unroll
        for (int kt = 0; kt < 4; kt++)
            Bf[kt] = *(const short8*)((const char*)xs + ((nr * 256 + kt * 64 + lg * 16) ^ ((nr & 7) << 4)));
        #pragma unroll
        for (int mh = 0; mh < 2; mh++) {
            f32x4 a0 = {0.f, 0.f, 0.f, 0.f}, a1 = {0.f, 0.f, 0.f, 0.f};
            #pragma unroll
            for (int kt = 0; kt < 4; kt++) {
                a0 = __builtin_amdgcn_mfma_f32_16x16x32_bf16(A1[mh * 2 + 0][kt], Bf[kt], a0, 0, 0, 0);
                a1 = __builtin_amdgcn_mfma_f32_16x16x32_bf16(A1[mh * 2 + 1][kt], Bf[kt], a1, 0, 0, 0);
            }
            float4 b0 = bb1[mh * 2 + 0], b1v = bb1[mh * 2 + 1];
            uint4 pkv;
            pkv.x = cvtpk(fmaxf(a0[0] + b0.x, 0.f),  fmaxf(a0[1] + b0.y, 0.f));
            pkv.y = cvtpk(fmaxf(a0[2] + b0.z, 0.f),  fmaxf(a0[3] + b0.w, 0.f));
            pkv.z = cvtpk(fmaxf(a1[0] + b1v.x, 0.f), fmaxf(a1[1] + b1v.y, 0.f));
            pkv.w = cvtpk(fmaxf(a1[2] + b1v.z, 0.f), fmaxf(a1[3] + b1v.w, 0.f));
            *(uint4*)((char*)hs + ((nr * 512 + wv * 128 + lg * 32 + mh * 16) ^ ((nr & 15) << 4))) = pkv;
        }
    }

    short8 A2[8];  // W2t rows wv*16+lr (loads stay in flight across barrier)
    #pragma unroll
    for (int kt = 0; kt < 8; kt++)
        A2[kt] = *(const short8*)(W2t + (size_t)(wv * 16 + lr) * 256 + kt * 32 + lg * 8);
    asm volatile("s_waitcnt lgkmcnt(0)" ::: "memory");
    __builtin_amdgcn_s_barrier();

    // ---- L2: h2b (wave owns out-col quarter wv*16) ----
    #pragma unroll
    for (int nj = 0; nj < 4; nj++) {
        short8 Bh[8];
        int nr = nj * 16 + lr;
        #pragma unroll
        for (int kt = 0; kt < 8; kt++)
            Bh[kt] = *(const short8*)((const char*)hs + ((nr * 512 + kt * 64 + lg * 16) ^ ((nr & 15) << 4)));
        int node = nb + nr;
        f32x4 acc = {0.f, 0.f, 0.f, 0.f};
        #pragma unroll
        for (int kt = 0; kt < 8; kt++)
            acc = __builtin_amdgcn_mfma_f32_16x16x32_bf16(A2[kt], Bh[kt], acc, 0, 0, 0);
        if (node < N_NODES) {
            uint2 u;
            u.x = cvtpk(acc[0], acc[1]);
            u.y = cvtpk(acc[2], acc[3]);
            *(uint2*)(h2b + (size_t)node * 64 + wv * 16 + lg * 4) = u;
        }
    }
}

// ---------------- fused edge MLP: pipelined, direct register gather from fb -------
// R13 structure + widened hid swizzle (er&15)<<4: hid rows are 512 B, the old
// (er&7)<<4 gave only 8 slots/16 lanes = 4-way bank conflict on b128 ops; 16
// slots -> ~2-way (free). Applied on BOTH write and read sides (bijective XOR).

__global__ __launch_bounds__(256) void k_edge_mlpC(
        const unsigned short* __restrict__ fb,
        const int* __restrict__ src, const int* __restrict__ dst,
        const short* __restrict__ Wp1t, const float* __restrict__ bp1,
        const short* __restrict__ Wp2t, const float* __restrict__ bp2,
        float* __restrict__ out, int n_tiles) {
    __shared__ unsigned short hid_s[2][32 * 256];  // 2 x 16 KB

    const int t = threadIdx.x;
    const int lane = t & 63, wv = t >> 6, lr = lane & 15, lg = lane >> 4;

    short8 A1[4][4];
    #pragma unroll
    for (int mi = 0; mi < 4; mi++)
        #pragma unroll
        for (int kt = 0; kt < 4; kt++)
            A1[mi][kt] = *(const short8*)(Wp1t + (size_t)(wv * 64 + mi * 16 + lr) * 128 + kt * 32 + lg * 8);
    short8 A2[8];
    #pragma unroll
    for (int kt = 0; kt < 8; kt++)
        A2[kt] = *(const short8*)(Wp2t + (size_t)(wv * 16 + lr) * 256 + kt * 32 + lg * 8);
    float4 bb1[4];
    #pragma unroll
    for (int mi = 0; mi < 4; mi++)
        bb1[mi] = *(const float4*)(bp1 + wv * 64 + mi * 16 + lg * 4);
    const float4 bv2 = *(const float4*)(bp2 + wv * 16 + lg * 4);

    int tile = blockIdx.x;
    if (tile >= n_tiles) return;
    const int g = gridDim.x;

    short8 Bf[2][4];
    {
        int sC[2], dC[2];
        #pragma unroll
        for (int nj = 0; nj < 2; nj++) {
            int e = tile * 32 + nj * 16 + lr;
            sC[nj] = src[e];
            dC[nj] = dst[e];
        }
        #pragma unroll
        for (int nj = 0; nj < 2; nj++) {
            const unsigned short* srow = fb + (size_t)sC[nj] * 64;
            const unsigned short* drow = fb + (size_t)dC[nj] * 64;
            Bf[nj][0] = *(const short8*)(srow + lg * 8);
            Bf[nj][1] = *(const short8*)(srow + 32 + lg * 8);
            Bf[nj][2] = *(const short8*)(drow + lg * 8);
            Bf[nj][3] = *(const short8*)(drow + 32 + lg * 8);
        }
    }
    int sA[2], dA[2];
    {
        int tn = tile + g;
        if (tn < n_tiles) {
            #pragma unroll
            for (int nj = 0; nj < 2; nj++) {
                int e = tn * 32 + nj * 16 + lr;
                sA[nj] = src[e];
                dA[nj] = dst[e];
            }
        }
    }

    int cur = 0;
    for (; tile < n_tiles; tile += g) {
        // ---- L1 phase: consume Bf, write hid_s[cur] ----
        #pragma unroll
        for (int nj = 0; nj < 2; nj++) {
            int er = nj * 16 + lr;
            #pragma unroll
            for (int mh = 0; mh < 2; mh++) {
                f32x4 a0 = {0.f, 0.f, 0.f, 0.f}, a1 = {0.f, 0.f, 0.f, 0.f};
                #pragma unroll
                for (int kt = 0; kt < 4; kt++) {
                    a0 = __builtin_amdgcn_mfma_f32_16x16x32_bf16(A1[mh * 2 + 0][kt], Bf[nj][kt], a0, 0, 0, 0);
                    a1 = __builtin_amdgcn_mfma_f32_16x16x32_bf16(A1[mh * 2 + 1][kt], Bf[nj][kt], a1, 0, 0, 0);
                }
                float4 b0 = bb1[mh * 2 + 0], b1v = bb1[mh * 2 + 1];
                uint4 pkv;
                pkv.x = cvtpk(fmaxf(a0[0] + b0.x, 0.f),  fmaxf(a0[1] + b0.y, 0.f));
                pkv.y = cvtpk(fmaxf(a0[2] + b0.z, 0.f),  fmaxf(a0[3] + b0.w, 0.f));
                pkv.z = cvtpk(fmaxf(a1[0] + b1v.x, 0.f), fmaxf(a1[1] + b1v.y, 0.f));
                pkv.w = cvtpk(fmaxf(a1[2] + b1v.z, 0.f), fmaxf(a1[3] + b1v.w, 0.f));
                *(uint4*)((char*)hid_s[cur] +
                    ((er * 512 + wv * 128 + lg * 32 + mh * 16) ^ ((er & 15) << 4))) = pkv;
            }
        }

        // ---- prefetch Bf(tile+g) (addresses ready from sA/dA) ----
        int tn = tile + g;
        if (tn < n_tiles) {
            #pragma unroll
            for (int nj = 0; nj < 2; nj++) {
                const unsigned short* srow = fb + (size_t)sA[nj] * 64;
                const unsigned short* drow = fb + (size_t)dA[nj] * 64;
                Bf[nj][0] = *(const short8*)(srow + lg * 8);
                Bf[nj][1] = *(const short8*)(srow + 32 + lg * 8);
                Bf[nj][2] = *(const short8*)(drow + lg * 8);
                Bf[nj][3] = *(const short8*)(drow + 32 + lg * 8);
            }
        }
        // ---- prefetch idx(tile+2g) ----
        int tnn = tile + 2 * g;
        if (tnn < n_tiles) {
            #pragma unroll
            for (int nj = 0; nj < 2; nj++) {
                int e = tnn * 32 + nj * 16 + lr;
                sA[nj] = src[e];
                dA[nj] = dst[e];
            }
        }

        asm volatile("s_waitcnt lgkmcnt(0)" ::: "memory");
        __builtin_amdgcn_s_barrier();

        // ---- L2 phase ----
        #pragma unroll
        for (int nj = 0; nj < 2; nj++) {
            short8 Bh[8];
            int er = nj * 16 + lr;
            #pragma unroll
            for (int kt = 0; kt < 8; kt++)
                Bh[kt] = *(const short8*)((const char*)hid_s[cur] +
                             ((er * 512 + kt * 64 + lg * 16) ^ ((er & 15) << 4)));
            f32x4 acc = {0.f, 0.f, 0.f, 0.f};
            #pragma unroll
            for (int kt = 0; kt < 8; kt++)
                acc = __builtin_amdgcn_mfma_f32_16x16x32_bf16(A2[kt], Bh[kt], acc, 0, 0, 0);
            float4 o = {acc[0] + bv2.x, acc[1] + bv2.y, acc[2] + bv2.z, acc[3] + bv2.w};
            *(float4*)(out + (size_t)(tile * 32 + er) * 64 + wv * 16 + lg * 4) = o;
        }
        cur ^= 1;
    }
}

// ---------------- launcher ----------------

extern "C" void kernel_launch(void* const* d_in, const int* in_sizes, int n_in,
                              void* d_out, int out_size, void* d_ws, size_t ws_size,
                              hipStream_t stream) {
    const float* x   = (const float*)d_in[0];
    const int*   ei  = (const int*)d_in[1];
    const float* W1  = (const float*)d_in[2];
    const float* b1  = (const float*)d_in[3];
    const float* W2  = (const float*)d_in[4];
    const float* b2  = (const float*)d_in[5];
    const float* Wp1 = (const float*)d_in[6];
    const float* bp1 = (const float*)d_in[7];
    const float* Wp2 = (const float*)d_in[8];
    const float* bp2 = (const float*)d_in[9];
    const float* Wc  = (const float*)d_in[10];
    const float* bc  = (const float*)d_in[11];

    const int* src = ei;
    const int* dst = ei + N_EDGES;

    float* out    = (float*)d_out;
    float* f_out  = out;                                   // [50000,64]
    float* ef_out = out + (size_t)N_NODES * OUT_DIM;       // [800000,64]
    float* lg_out = ef_out + (size_t)N_EDGES * OUT_DIM;    // [50000,40]
    float* ei_out = lg_out + (size_t)N_NODES * N_CLASSES;  // [2,800000]

    char* p = (char*)d_ws;
    auto alloc = [&](size_t bytes) -> char* {
        char* r = p;
        p += (bytes + 255) / 256 * 256;
        return r;
    };
    unsigned short* xb   = (unsigned short*)alloc((size_t)N_NODES * IN_DIM * 2);
    unsigned short* xa   = (unsigned short*)alloc((size_t)N_NODES * IN_DIM * 2);
    unsigned short* h2b  = (unsigned short*)alloc((size_t)N_NODES * OUT_DIM * 2);
    unsigned short* fb   = (unsigned short*)alloc((size_t)N_NODES * OUT_DIM * 2);
    int*   degi    = (int*)alloc((size_t)N_NODES * 4);
    float* dinv    = (float*)alloc((size_t)N_NODES * 4);
    int*   csr_off = (int*)alloc((size_t)(N_NODES + 1) * 4);
    int*   cursor  = (int*)alloc((size_t)N_NODES * 4);
    int*   csr_src = (int*)alloc((size_t)N_EDGES * 4);
    int*   bsum    = (int*)alloc(256 * 4);
    short* W1t     = (short*)alloc((size_t)256 * 128 * 2);
    short* W2t     = (short*)alloc((size_t)64 * 256 * 2);
    short* Wp1t    = (short*)alloc((size_t)256 * 128 * 2);
    short* Wp2t    = (short*)alloc((size_t)64 * 256 * 2);

    const int nbScan = (N_NODES + 255) / 256;  // 196

    k_prep<<<(N_NODES * IN_DIM / 4 + 255) / 256, 256, 0, stream>>>(
        x, ei, W1, W2, Wp1, Wp2, xb, W1t, W2t, Wp1t, Wp2t, degi, cursor, ei_out);
    k_deg_count<<<(N_EDGES + 255) / 256, 256, 0, stream>>>(dst, degi);
    k_scan_bsum<<<nbScan, 256, 0, stream>>>(degi, N_NODES, bsum, dinv);
    k_scan_bscan<<<1, 256, 0, stream>>>(bsum, nbScan);
    k_scan_final<<<nbScan, 256, 0, stream>>>(degi, N_NODES, bsum, csr_off);
    k_csr_fill<<<(N_EDGES + 255) / 256, 256, 0, stream>>>(src, dst, csr_off, cursor, csr_src);

    const int nbG = (N_NODES + 63) / 64;  // 782
    k_agg0<<<N_NODES / 4, 256, 0, stream>>>(xb, dinv, csr_off, csr_src, xa);
    k_gemm12<<<nbG, 256, 0, stream>>>(xa, W1t, b1, W2t, h2b);
    k_agg2<<<N_NODES / 4, 256, 0, stream>>>(h2b, dinv, csr_off, csr_src, b2, Wc, bc,
                                            f_out, fb, lg_out);

    k_edge_mlpC<<<1280, 256, 0, stream>>>(fb, src, dst, Wp1t, bp1, Wp2t, bp2,
                                          ef_out, N_EDGES / 32);
}